// Round 8
// baseline (1874.833 us; speedup 1.0000x reference)
//
#include <hip/hip_runtime.h>
#include <cstdint>

// SelfMatchingLayer: B=32, L=512, H=256, fp32.
// R9: k7 rewritten on MFMA. R5-R8 lesson: the allocator never gives >128
//     arch VGPRs; 192-u32/thread fdot2 weights land in scratch (~135/thr),
//     whose per-step L2 reloads (~1000cy VMEM issue) pin k7 at ~3000cy/step.
//     MFMA B-operands read AGPRs natively -> weights in AGPRs with NO
//     bounce and NO scratch. 8 blocks = (dir x 4 groups of 8 seqs); per
//     step: gh(16x768) = h(16x256) @ Whh^T via mfma_f32_16x16x32_f16
//     (M=16: 8 real + 8 zero rows), 48 mfma/wave; D->gh LDS; GRU (fp32,
//     4 elems/thread); h fp16 -> LDS; A-frags reloaded (8x b128). gi
//     prefetched via global_load_lds, source-XOR-swizzled (LDS linear).
//     D-layout per verified m89; A/B packed with identical k-rule so any
//     k-permutation error cancels. k1-k6 unchanged.

#define LL 512
#define HH 256

typedef _Float16 half2_t __attribute__((ext_vector_type(2)));
typedef _Float16 f16x8   __attribute__((ext_vector_type(8)));
typedef float    f32x4   __attribute__((ext_vector_type(4)));

__device__ __forceinline__ float exp2f_fast(float x){
#if defined(__HIP_DEVICE_COMPILE__)
  return __builtin_amdgcn_exp2f(x);
#else
  return exp2f(x);
#endif
}
__device__ __forceinline__ float rcpf_fast(float x){
#if defined(__HIP_DEVICE_COMPILE__)
  return __builtin_amdgcn_rcpf(x);
#else
  return 1.0f/x;
#endif
}
__device__ __forceinline__ float tanh_fast(float x){
  float e = exp2f_fast(x * 2.885390081777927f);   // 2*log2(e)
  return 1.0f - 2.0f * rcpf_fast(1.0f + e);
}
__device__ __forceinline__ float sigmoid_fast(float x){
  return rcpf_fast(1.0f + exp2f_fast(x * -1.4426950408889634f));
}

#define SCALE_K2 2.885390081777927f   // 2*log2(e)

#if defined(__HIP_DEVICE_COMPILE__) && __has_builtin(__builtin_amdgcn_fdot2)
#define USE_FDOT2 1
#endif

__device__ __forceinline__ float dot2_acc(unsigned wb, unsigned hb, float a){
  half2_t wv = __builtin_bit_cast(half2_t, wb);
  half2_t hv = __builtin_bit_cast(half2_t, hb);
#ifdef USE_FDOT2
  return __builtin_amdgcn_fdot2(wv, hv, a, false);
#else
  return a + (float)wv.x*(float)hv.x + (float)wv.y*(float)hv.y;
#endif
}

__device__ __forceinline__ unsigned pack2h(float a, float b){
  half2_t h = { (_Float16)a, (_Float16)b };
  return __builtin_bit_cast(unsigned, h);
}
__device__ __forceinline__ f16x8 pack8(float4 a, float4 b){
  f16x8 v;
  v[0]=(_Float16)a.x; v[1]=(_Float16)a.y; v[2]=(_Float16)a.z; v[3]=(_Float16)a.w;
  v[4]=(_Float16)b.x; v[5]=(_Float16)b.y; v[6]=(_Float16)b.z; v[7]=(_Float16)b.w;
  return v;
}
__device__ __forceinline__ void gload_lds16(const float* src, float* dst){
  __builtin_amdgcn_global_load_lds(
      (const __attribute__((address_space(1))) void*)src,
      (__attribute__((address_space(3))) void*)dst,
      16, 0, 0);
}

// ==== fp32 128x128-tile GEMM helpers (k1 only) ===========================
__device__ __forceinline__ void stage_t128(float* Ls, const float* g, int ldg){
  int tid = threadIdx.x;
  int r = tid >> 4, kq = (tid & 15) * 4;
  #pragma unroll
  for (int it = 0; it < 8; it++){
    int rr = r + 16*it;
    float4 v = *(const float4*)(g + (size_t)rr*ldg + kq);
    Ls[(kq+0)*132 + rr] = v.x;
    Ls[(kq+1)*132 + rr] = v.y;
    Ls[(kq+2)*132 + rr] = v.z;
    Ls[(kq+3)*132 + rr] = v.w;
  }
}
__device__ __forceinline__ void rg_inner128(const float* Xs, const float* Ws,
                                            float (&acc)[8][8], int rg, int cg){
  #pragma unroll 2
  for (int k = 0; k < 64; k++){
    const float* xr = Xs + k*132;
    const float* wr = Ws + k*132;
    float4 x0 = *(const float4*)(xr + rg*4);
    float4 x1 = *(const float4*)(xr + 64 + rg*4);
    float4 w0 = *(const float4*)(wr + cg*4);
    float4 w1 = *(const float4*)(wr + 64 + cg*4);
    float xv[8] = {x0.x,x0.y,x0.z,x0.w, x1.x,x1.y,x1.z,x1.w};
    float wv[8] = {w0.x,w0.y,w0.z,w0.w, w1.x,w1.y,w1.z,w1.w};
    #pragma unroll
    for (int i=0;i<8;i++)
      #pragma unroll
      for (int j=0;j<8;j++)
        acc[i][j] = fmaf(xv[i], wv[j], acc[i][j]);
  }
}
#define ROW_OF(i, rg) ((rg)*4 + ((i)&3) + ((i)>>2)*64)
#define COL_OF(j, cg) ((cg)*4 + ((j)&3) + ((j)>>2)*64)

// ==== packed-fp16 128x128-tile GEMM helpers (k4/k5/k6) ===================
__device__ __forceinline__ void stage_t128_h(unsigned* Ls, const float* g, int ldg){
  int tid = threadIdx.x;
  int r = tid >> 4, kq = (tid & 15) * 4;
  #pragma unroll
  for (int it = 0; it < 8; it++){
    int rr = r + 16*it;
    float4 v = *(const float4*)(g + (size_t)rr*ldg + kq);
    Ls[((kq>>1)+0)*132 + rr] = pack2h(v.x, v.y);
    Ls[((kq>>1)+1)*132 + rr] = pack2h(v.z, v.w);
  }
}
__device__ __forceinline__ void stage_dpack_h(unsigned* Ls, const float* g, int ldg){
  int tid = threadIdx.x;
  int kr = tid >> 5, eq = (tid & 31) * 4;
  #pragma unroll
  for (int it = 0; it < 4; it++){
    int lp = kr + 8*it;
    float4 a = *(const float4*)(g + (size_t)(2*lp  )*ldg + eq);
    float4 b = *(const float4*)(g + (size_t)(2*lp+1)*ldg + eq);
    uint4 o;
    o.x = pack2h(a.x, b.x);
    o.y = pack2h(a.y, b.y);
    o.z = pack2h(a.z, b.z);
    o.w = pack2h(a.w, b.w);
    *(uint4*)(Ls + lp*132 + eq) = o;
  }
}
__device__ __forceinline__ void rg_inner128_h(const unsigned* Xs, const unsigned* Ws,
                                              float (&acc)[8][8], int rg, int cg){
  #pragma unroll 2
  for (int kp = 0; kp < 32; kp++){
    const unsigned* xr = Xs + kp*132;
    const unsigned* wr = Ws + kp*132;
    uint4 x0 = *(const uint4*)(xr + rg*4);
    uint4 x1 = *(const uint4*)(xr + 64 + rg*4);
    uint4 w0 = *(const uint4*)(wr + cg*4);
    uint4 w1 = *(const uint4*)(wr + 64 + cg*4);
    unsigned xv[8] = {x0.x,x0.y,x0.z,x0.w, x1.x,x1.y,x1.z,x1.w};
    unsigned wv[8] = {w0.x,w0.y,w0.z,w0.w, w1.x,w1.y,w1.z,w1.w};
    #pragma unroll
    for (int i=0;i<8;i++)
      #pragma unroll
      for (int j=0;j<8;j++)
        acc[i][j] = dot2_acc(xv[i], wv[j], acc[i][j]);
  }
}

// ---------------- K1: HQ' = SC*(P@wq^T+bq) ; PP' = SC*(P@wp^T+bp) --------
__global__ __launch_bounds__(256) void k1_hq_pp(
    const float* __restrict__ P,
    const float* __restrict__ wq_w, const float* __restrict__ wq_b,
    const float* __restrict__ wp_w, const float* __restrict__ wp_b,
    float* __restrict__ HQ, float* __restrict__ PP)
{
  __shared__ __align__(16) float Xs[64*132];
  __shared__ __align__(16) float Ws[64*132];
  int rt = blockIdx.x, ct = blockIdx.y;
  const float* W  = (ct < 2) ? wq_w : wp_w;
  const float* Bv = (ct < 2) ? wq_b : wp_b;
  float* O = (ct < 2) ? HQ : PP;
  int c0 = (ct & 1) * 128, r0 = rt * 128;
  int tid = threadIdx.x, rg = tid & 15, cg = tid >> 4;
  float acc[8][8];
  #pragma unroll
  for (int i=0;i<8;i++)
    #pragma unroll
    for (int j=0;j<8;j++) acc[i][j]=0.f;
  for (int kc = 0; kc < 4; kc++){
    __syncthreads();
    stage_t128(Xs, P + (size_t)r0*HH + kc*64, HH);
    stage_t128(Ws, W + (size_t)c0*HH + kc*64, HH);
    __syncthreads();
    rg_inner128(Xs, Ws, acc, rg, cg);
  }
  float bj[8];
  #pragma unroll
  for (int j=0;j<8;j++) bj[j] = Bv[c0 + COL_OF(j,cg)];
  #pragma unroll
  for (int i=0;i<8;i++){
    int r = r0 + ROW_OF(i,rg);
    #pragma unroll
    for (int j=0;j<8;j++)
      O[(size_t)r*HH + c0 + COL_OF(j,cg)] = SCALE_K2 * (acc[i][j] + bj[j]);
  }
}

// ---------------- K2: S_eff[b,t,l] = -2 * sum_h w_h / (1 + exp2(HQ'+PP')) -
__global__ __launch_bounds__(256) void k2_scores(
    const float* __restrict__ HQ, const float* __restrict__ PP,
    const float* __restrict__ ws_w, float* __restrict__ S)
{
  __shared__ float Hq_c[128*65];
  __shared__ float Pp_c[32*65];
  __shared__ float wsl[256];
  int tid = threadIdx.x;
  int b = blockIdx.y, t0 = blockIdx.x * 32;
  wsl[tid] = ws_w[tid];
  int tg = tid >> 6;
  int lg = tid & 63;
  for (int lc = 0; lc < 4; lc++){
    float acc[8][2];
    #pragma unroll
    for (int i=0;i<8;i++){ acc[i][0]=0.f; acc[i][1]=0.f; }
    for (int hc = 0; hc < 4; hc++){
      __syncthreads();
      {
        int r = tid >> 4, kq = (tid & 15) * 4;
        #pragma unroll
        for (int it=0; it<2; it++){
          int t = r + 16*it;
          float4 v = *(const float4*)(PP + ((size_t)b*LL + t0 + t)*HH + hc*64 + kq);
          float* d = Pp_c + t*65 + kq;
          d[0]=v.x; d[1]=v.y; d[2]=v.z; d[3]=v.w;
        }
      }
      {
        int r = tid >> 4, kq = (tid & 15) * 4;
        #pragma unroll
        for (int it=0; it<8; it++){
          int l = r + 16*it;
          float4 v = *(const float4*)(HQ + ((size_t)b*LL + lc*128 + l)*HH + hc*64 + kq);
          float* d = Hq_c + l*65 + kq;
          d[0]=v.x; d[1]=v.y; d[2]=v.z; d[3]=v.w;
        }
      }
      __syncthreads();
      #pragma unroll 2
      for (int h = 0; h < 64; h++){
        float w = wsl[hc*64 + h];
        float pp[8], hq[2];
        #pragma unroll
        for (int i=0;i<8;i++) pp[i] = Pp_c[(tg + 4*i)*65 + h];
        #pragma unroll
        for (int j=0;j<2;j++) hq[j] = Hq_c[(2*lg + j)*65 + h];
        #pragma unroll
        for (int i=0;i<8;i++)
          #pragma unroll
          for (int j=0;j<2;j++){
            float e = exp2f_fast(pp[i] + hq[j]);
            acc[i][j] = fmaf(w, rcpf_fast(1.0f + e), acc[i][j]);
          }
      }
    }
    #pragma unroll
    for (int i=0;i<8;i++)
      #pragma unroll
      for (int j=0;j<2;j++)
        S[((size_t)b*LL + t0 + tg + 4*i)*LL + lc*128 + 2*lg + j] = -2.0f*acc[i][j];
    __syncthreads();
  }
}

// ---------------- K3: softmax over l, in place; one wave per row ----------
__global__ __launch_bounds__(256) void k3_softmax(float* __restrict__ S)
{
  int wave = threadIdx.x >> 6, lane = threadIdx.x & 63;
  size_t row = (size_t)blockIdx.x*4 + wave;
  float* p = S + row*LL;
  float v[8];
  #pragma unroll
  for (int i=0;i<8;i++) v[i] = p[lane + 64*i];
  float m = v[0];
  #pragma unroll
  for (int i=1;i<8;i++) m = fmaxf(m, v[i]);
  #pragma unroll
  for (int off=32; off>=1; off>>=1) m = fmaxf(m, __shfl_xor(m, off, 64));
  float s = 0.f;
  #pragma unroll
  for (int i=0;i<8;i++){ v[i] = exp2f_fast((v[i]-m)*1.4426950408889634f); s += v[i]; }
  #pragma unroll
  for (int off=32; off>=1; off>>=1) s += __shfl_xor(s, off, 64);
  float inv = 1.0f / s;
  #pragma unroll
  for (int i=0;i<8;i++) p[lane + 64*i] = v[i]*inv;
}

// ---------------- K4: C[b,t,:] = attn[b,t,:] @ P[b,:,:] (fdot2) -----------
__global__ __launch_bounds__(256, 4) void k4_context(
    const float* __restrict__ S, const float* __restrict__ P, float* __restrict__ C)
{
  __shared__ __align__(16) unsigned As[32*132];
  __shared__ __align__(16) unsigned Ps[32*132];
  int j0 = blockIdx.x * 128, t0 = blockIdx.y * 128, b = blockIdx.z;
  int tid = threadIdx.x, rg = tid & 15, cg = tid >> 4;
  float acc[8][8];
  #pragma unroll
  for (int i=0;i<8;i++)
    #pragma unroll
    for (int j=0;j<8;j++) acc[i][j]=0.f;
  for (int lc = 0; lc < 8; lc++){
    int l0 = lc*64;
    __syncthreads();
    stage_t128_h (As, S + ((size_t)b*LL + t0)*LL + l0, LL);
    stage_dpack_h(Ps, P + ((size_t)b*LL + l0)*HH + j0, HH);
    __syncthreads();
    rg_inner128_h(As, Ps, acc, rg, cg);
  }
  #pragma unroll
  for (int i=0;i<8;i++){
    int t = t0 + ROW_OF(i,rg);
    #pragma unroll
    for (int j=0;j<8;j++)
      C[((size_t)b*LL + t)*HH + j0 + COL_OF(j,cg)] = acc[i][j];
  }
}

// ---------------- K5: Cg = sigmoid([P|C]@wg^T + bg) * C (fdot2) -----------
__global__ __launch_bounds__(256, 4) void k5_gate(
    const float* __restrict__ P, const float* __restrict__ C,
    const float* __restrict__ wg_w, const float* __restrict__ wg_b,
    float* __restrict__ CG)
{
  __shared__ __align__(16) unsigned Xs[32*132];
  __shared__ __align__(16) unsigned Ws[32*132];
  int r0 = blockIdx.x*128, c0 = blockIdx.y*128;
  int tid = threadIdx.x, rg = tid & 15, cg = tid >> 4;
  float acc[8][8];
  #pragma unroll
  for (int i=0;i<8;i++)
    #pragma unroll
    for (int j=0;j<8;j++) acc[i][j]=0.f;
  for (int kc = 0; kc < 8; kc++){
    const float* Xsrc = (kc < 4) ? (P + (size_t)r0*HH + kc*64)
                                 : (C + (size_t)r0*HH + (kc-4)*64);
    __syncthreads();
    stage_t128_h(Xs, Xsrc, HH);
    stage_t128_h(Ws, wg_w + (size_t)c0*(2*HH) + kc*64, 2*HH);
    __syncthreads();
    rg_inner128_h(Xs, Ws, acc, rg, cg);
  }
  float bj[8];
  #pragma unroll
  for (int j=0;j<8;j++) bj[j] = wg_b[c0 + COL_OF(j,cg)];
  #pragma unroll
  for (int i=0;i<8;i++){
    int r = r0 + ROW_OF(i,rg);
    #pragma unroll
    for (int j=0;j<8;j++){
      int c = c0 + COL_OF(j,cg);
      float g = sigmoid_fast(acc[i][j] + bj[j]);
      CG[(size_t)r*HH + c] = g * C[(size_t)r*HH + c];
    }
  }
}

// ---------------- K6: GI_{l,r} = Cg @ Wih^T + bih (fdot2) -----------------
__global__ __launch_bounds__(256, 4) void k6_gi(
    const float* __restrict__ CG,
    const float* __restrict__ Wih_l, const float* __restrict__ bih_l,
    const float* __restrict__ Wih_r, const float* __restrict__ bih_r,
    float* __restrict__ GIL, float* __restrict__ GIR)
{
  __shared__ __align__(16) unsigned Xs[32*132];
  __shared__ __align__(16) unsigned Ws[32*132];
  int rt = blockIdx.x, ct = blockIdx.y;
  int dir = (ct >= 6);
  const float* Wih = dir ? Wih_r : Wih_l;
  const float* bih = dir ? bih_r : bih_l;
  float* GI = dir ? GIR : GIL;
  int c0 = (ct % 6) * 128, r0 = rt * 128;
  int tid = threadIdx.x, rg = tid & 15, cg = tid >> 4;
  float acc[8][8];
  #pragma unroll
  for (int i=0;i<8;i++)
    #pragma unroll
    for (int j=0;j<8;j++) acc[i][j]=0.f;
  for (int kc = 0; kc < 4; kc++){
    __syncthreads();
    stage_t128_h(Xs, CG + (size_t)r0*HH + kc*64, HH);
    stage_t128_h(Ws, Wih + (size_t)c0*HH + kc*64, HH);
    __syncthreads();
    rg_inner128_h(Xs, Ws, acc, rg, cg);
  }
  float bj[8];
  #pragma unroll
  for (int j=0;j<8;j++) bj[j] = bih[c0 + COL_OF(j,cg)];
  #pragma unroll
  for (int i=0;i<8;i++){
    int r = r0 + ROW_OF(i,rg);
    #pragma unroll
    for (int j=0;j<8;j++)
      GI[(size_t)r*768 + c0 + COL_OF(j,cg)] = acc[i][j] + bj[j];
  }
}

// ---------------- K7: GRU scans (R9, MFMA) --------------------------------
// 8 blocks = (dir, grp). Seqs b = grp*8..grp*8+7 (M rows 8..15 are zero
// padding). Per step: gh = h @ Whh^T via mfma_f32_16x16x32_f16.
// Wave w owns gh-cols [w*96, w*96+96): B-frags 6nt x 8kt (192 regs, AGPR).
// A-frag: lane l row=l&15, k=(l>>4)*8+e; B: col=l&15, same k rule ->
// any k-permutation error cancels. D: col=l&15, row=(l>>4)*4+reg (m89).
// gi staged via global_load_lds double-buffer, source-XOR-swizzled
// (chunk q -> q^seq) so GRU reads are 8-beat optimal; LDS stays linear.
__global__ __launch_bounds__(512, 2) void k7_scan(
    const float* __restrict__ GIL, const float* __restrict__ GIR,
    const float* __restrict__ Whh_l, const float* __restrict__ bhh_l,
    const float* __restrict__ Whh_r, const float* __restrict__ bhh_r,
    float* __restrict__ out)
{
  int dir = blockIdx.x & 1;
  int grp = blockIdx.x >> 1;          // 0..3
  int t = threadIdx.x;
  int w = t >> 6, l = t & 63;
  const float* GI  = dir ? GIR : GIL;
  const float* Whh = dir ? Whh_r : Whh_l;
  const float* bhh = dir ? bhh_r : bhh_l;

  __shared__ __align__(16) float    gi_buf[2][8*768];   // 48 KB (swizzled)
  __shared__ __align__(16) float    gh[16*772];         // 48.3 KB
  __shared__ __align__(16) unsigned h2[16*132];         // 8.25 KB (fp16 h)
  __shared__ __align__(16) float    bias[768];          // 3 KB

  // ---- B-frags (weights). B[k][c] = Whh[c][k]; c = w*96+nt*16+(l&15),
  // k = kt*32 + (l>>4)*8 + e.
  f16x8 Bf[48];
  {
    int cb = w*96 + (l & 15);
    int kb = (l >> 4) * 8;
    #pragma unroll
    for (int nt = 0; nt < 6; nt++)
      #pragma unroll
      for (int kt = 0; kt < 8; kt++){
        const float* s = Whh + (size_t)(cb + nt*16)*HH + kt*32 + kb;
        float4 a = *(const float4*)s;
        float4 b = *(const float4*)(s + 4);
        Bf[nt*8+kt] = pack8(a, b);
      }
  }
  for (int i = t; i < 16*132; i += 512) h2[i] = 0;
  for (int i = t; i < 768;    i += 512) bias[i] = bhh[i];

  f16x8 zf;
  #pragma unroll
  for (int e = 0; e < 8; e++) zf[e] = (_Float16)0.0f;
  f16x8 Af[8];
  #pragma unroll
  for (int kt = 0; kt < 8; kt++) Af[kt] = zf;

  // prologue: stage gi[step 0] into buf 0 (source-swizzled, LDS linear)
  {
    int tt0 = dir ? (LL-1) : 0;
    #pragma unroll
    for (int i = 0; i < 3; i++){
      int c  = (w*3 + i)*64 + l;           // float4 chunk 0..1535
      int sq = c / 192;
      int q  = (c - sq*192) ^ sq;
      const float* src = GI + ((size_t)(grp*8 + sq)*LL + tt0)*768 + q*4;
      gload_lds16(src, &gi_buf[0][(w*3+i)*256]);
    }
  }
  asm volatile("s_waitcnt vmcnt(0)" ::: "memory");
  __syncthreads();

  int sq = t & 7;            // GRU: sequence
  int jj = t >> 3;           // 0..63
  int u0 = jj * 4;           // GRU: 4 outputs u0..u0+3

  for (int s = 0; s < LL; s++){
    int bi = s & 1;
    // [a] prefetch next step's gi into the other buffer
    if (s < LL-1){
      int tn = dir ? (LL-2-s) : (s+1);
      #pragma unroll
      for (int i = 0; i < 3; i++){
        int c  = (w*3 + i)*64 + l;
        int s2 = c / 192;
        int q  = (c - s2*192) ^ s2;
        const float* src = GI + ((size_t)(grp*8 + s2)*LL + tn)*768 + q*4;
        gload_lds16(src, &gi_buf[bi^1][(w*3+i)*256]);
      }
    }
    // [b] MFMA: gh = h @ Whh^T  (D -> gh LDS)
    {
      int cb = w*96 + (l & 15);
      int r0 = (l >> 4)*4;
      #pragma unroll
      for (int nt = 0; nt < 6; nt++){
        f32x4 d = {0.f, 0.f, 0.f, 0.f};
        #pragma unroll
        for (int kt = 0; kt < 8; kt++)
          d = __builtin_amdgcn_mfma_f32_16x16x32_f16(Af[kt], Bf[nt*8+kt], d, 0, 0, 0);
        int cc = cb + nt*16;
        gh[(r0+0)*772 + cc] = d[0];
        gh[(r0+1)*772 + cc] = d[1];
        gh[(r0+2)*772 + cc] = d[2];
        gh[(r0+3)*772 + cc] = d[3];
      }
    }
    // [c] gh visible; gi[s+1] landed
    asm volatile("s_waitcnt vmcnt(0)" ::: "memory");
    __syncthreads();
    // [d] GRU for (sq, u0..u0+3)
    {
      int tt = dir ? (LL-1-s) : s;
      float4 ghr = *(const float4*)&gh[sq*772 +       u0];
      float4 ghz = *(const float4*)&gh[sq*772 + 256 + u0];
      float4 ghn = *(const float4*)&gh[sq*772 + 512 + u0];
      const float* gb = gi_buf[bi] + sq*768;
      float4 gir = *(const float4*)&gb[((  0 + jj) ^ sq)*4];
      float4 giz = *(const float4*)&gb[(( 64 + jj) ^ sq)*4];
      float4 gin = *(const float4*)&gb[((128 + jj) ^ sq)*4];
      float4 bR  = *(const float4*)&bias[      u0];
      float4 bZ  = *(const float4*)&bias[256 + u0];
      float4 bN  = *(const float4*)&bias[512 + u0];
      uint2 hp = *(const uint2*)&h2[sq*132 + (u0>>1)];
      half2_t h0 = __builtin_bit_cast(half2_t, hp.x);
      half2_t h1 = __builtin_bit_cast(half2_t, hp.y);
      float hpv0 = (float)h0.x, hpv1 = (float)h0.y;
      float hpv2 = (float)h1.x, hpv3 = (float)h1.y;
      float r0v = sigmoid_fast(gir.x + ghr.x + bR.x);
      float r1v = sigmoid_fast(gir.y + ghr.y + bR.y);
      float r2v = sigmoid_fast(gir.z + ghr.z + bR.z);
      float r3v = sigmoid_fast(gir.w + ghr.w + bR.w);
      float z0v = sigmoid_fast(giz.x + ghz.x + bZ.x);
      float z1v = sigmoid_fast(giz.y + ghz.y + bZ.y);
      float z2v = sigmoid_fast(giz.z + ghz.z + bZ.z);
      float z3v = sigmoid_fast(giz.w + ghz.w + bZ.w);
      float n0v = tanh_fast(gin.x + r0v*(ghn.x + bN.x));
      float n1v = tanh_fast(gin.y + r1v*(ghn.y + bN.y));
      float n2v = tanh_fast(gin.z + r2v*(ghn.z + bN.z));
      float n3v = tanh_fast(gin.w + r3v*(ghn.w + bN.w));
      float hn0 = z0v*(hpv0 - n0v) + n0v;
      float hn1 = z1v*(hpv1 - n1v) + n1v;
      float hn2 = z2v*(hpv2 - n2v) + n2v;
      float hn3 = z3v*(hpv3 - n3v) + n3v;
      float4 o; o.x = hn0; o.y = hn1; o.z = hn2; o.w = hn3;
      *(float4*)(out + ((size_t)(grp*8 + sq)*LL + tt)*(2*HH) + dir*HH + u0) = o;
      uint2 hw;
      hw.x = pack2h(hn0, hn1);
      hw.y = pack2h(hn2, hn3);
      *(uint2*)&h2[sq*132 + (u0>>1)] = hw;
    }
    // [e] h ready; load A-frags for next step
    __syncthreads();
    #pragma unroll
    for (int kt = 0; kt < 8; kt++){
      uint4 q = *(const uint4*)&h2[(l&15)*132 + kt*16 + (l>>4)*4];
      Af[kt] = __builtin_bit_cast(f16x8, q);
    }
  }
}

extern "C" void kernel_launch(void* const* d_in, const int* in_sizes, int n_in,
                              void* d_out, int out_size, void* d_ws, size_t ws_size,
                              hipStream_t stream)
{
  const float* P    = (const float*)d_in[0];
  const float* wq_w = (const float*)d_in[1];
  const float* wq_b = (const float*)d_in[2];
  const float* wp_w = (const float*)d_in[3];
  const float* wp_b = (const float*)d_in[4];
  const float* ws_w = (const float*)d_in[5];
  // d_in[6] = ws_b: softmax-invariant, unused
  const float* wg_w = (const float*)d_in[7];
  const float* wg_b = (const float*)d_in[8];
  const float* Wih_l= (const float*)d_in[9];
  const float* Whh_l= (const float*)d_in[10];
  const float* bih_l= (const float*)d_in[11];
  const float* bhh_l= (const float*)d_in[12];
  const float* Wih_r= (const float*)d_in[13];
  const float* Whh_r= (const float*)d_in[14];
  const float* bih_r= (const float*)d_in[15];
  const float* bhh_r= (const float*)d_in[16];

  float* ws  = (float*)d_ws;
  float* HQ  = ws;                    //  4,194,304
  float* PP  = ws + 4194304;          //  4,194,304
  float* S   = ws + 8388608;          //  8,388,608
  float* C   = ws + 16777216;         //  4,194,304
  float* CG  = ws + 20971520;         //  4,194,304
  float* GIR = ws + 25165824;         // 12,582,912
  float* GIL = ws;                    // 12,582,912 (aliases HQ/PP/S-front; dead by k6)
  float* out = (float*)d_out;

  k1_hq_pp  <<<dim3(128, 4),    256, 0, stream>>>(P, wq_w, wq_b, wp_w, wp_b, HQ, PP);
  k2_scores <<<dim3(16, 32),    256, 0, stream>>>(HQ, PP, ws_w, S);
  k3_softmax<<<4096,            256, 0, stream>>>(S);
  k4_context<<<dim3(2, 4, 32),  256, 0, stream>>>(S, P, C);
  k5_gate   <<<dim3(128, 2),    256, 0, stream>>>(P, C, wg_w, wg_b, CG);
  k6_gi     <<<dim3(128, 12),   256, 0, stream>>>(CG, Wih_l, bih_l, Wih_r, bih_r, GIL, GIR);
  k7_scan   <<<8,               512, 0, stream>>>(GIL, GIR, Whh_l, bhh_l, Whh_r, bhh_r, out);
}